// Round 15
// baseline (457.237 us; speedup 1.0000x reference)
//
#include <hip/hip_runtime.h>
#include <hip/hip_bf16.h>
#include <stdint.h>

typedef unsigned int uint_t;
typedef unsigned short ushort_t;

#define NN 100000
#define EE 1600000
#define CC 25000
#define DINTER 144
#define NBKT 196          // C-side coarse buckets: src cluster >> 7
#define NBKT2 1568        // A-side buckets: (src_node/12500)*196 + (dst_node>>9)
#define NSEG 6272         // dedupe segments: 196 buckets * 32 subs (4 u-clusters each)
#define KCAP 1024         // keys per segment cap (mean 256, sigma 16 -> +48 sigma)

// ---- ws layout in 32-bit words (total 92.27 MB, proven) ----
#define W_M1B      0u         // u16 [131*128] bf16 m1 = 8384 words
#define W_AGGB     8384u      // pkW sorted keys region (u32 [1,600,000] fits in 1,650,000)
#define W_PAGG     1658384u   // bf16[8][25000*132] = 13,200,000 words (kbuf reuse after gemm)
#define W_PKA4     14858384u  // uint4[1,600,000] = 6,400,000 words (csub/bcnt/ebase reuse after sort)
#define W_PKC      21258384u  // u32 [1600000]
#define W_OFFS2    22858384u  // u32 [200001]  per-(slice,cluster) segment offsets
#define W_BHA2     23058385u  // u32 [1568]
#define W_BHC      23059953u  // u32 [196]   (adjacent to BHA2: one memset of 1764)
#define W_BBA2     23060149u  // u32 [1569]
#define W_BCURA2   23061718u  // u32 [1568]
#define W_BBC      23063286u  // u32 [197]
#define W_BCURC    23063483u  // u32 [196]
#define WS_WORDS   23066816u

// ---- out layout in FLOAT32 elements (total 11,300,000) ----
#define O_XNEW  0u
#define O_POS   3200000u
#define O_EI    3275000u
#define O_ATTR  6475000u
#define O_BATCH 11275000u
// x_bf16 staging: first 6.4M words of the O_EI region (tails zeroed by tail_zero)
// new_pos f32[25000*3] lives at out[O_POS] and is read back by enc_emit.

static __device__ __forceinline__ uint_t f2bf(float f) {
    union { float f; uint_t i; } v; v.f = f;
    uint_t x = v.i;
    return (x + 0x7fffu + ((x >> 16) & 1u)) >> 16;  // RNE
}
static __device__ __forceinline__ float bf2f(ushort_t u) {
    union { uint_t i; float f; } v; v.i = ((uint_t)u) << 16; return v.f;
}

// K0: pack x (f32) -> bf16x2 words into the output-staging region.
__global__ void xpack(const float4* __restrict__ x4, uint2* __restrict__ xb2) {
    int i = blockIdx.x * 256 + threadIdx.x;
    if (i >= NN * 32) return;            // 12.8M floats / 4
    float4 v = x4[i];
    uint2 r;
    r.x = f2bf(v.x) | (f2bf(v.y) << 16);
    r.y = f2bf(v.z) | (f2bf(v.w) << 16);
    xb2[i] = r;
}

// K1: M1[j][o] = sum_f Wrow_j[f] * Wg[f][o], emitted directly as bf16.
__global__ void build_m1f(const float* __restrict__ Wconv,
                          const float* __restrict__ Wedge,
                          const float* __restrict__ Wg,
                          ushort_t* __restrict__ m1b) {
    int j = blockIdx.x;   // 0..130
    int o = threadIdx.x;  // 0..127
    const float* wrow = (j < 128) ? (Wconv + j * DINTER + 16)
                                  : (Wedge + (j - 128) * DINTER + 16);
    float acc = 0.f;
    for (int f = 0; f < 128; ++f)
        acc += wrow[f] * Wg[f * 128 + o];
    m1b[j * 128 + o] = (ushort_t)f2bf(acc);
}

// K2a: fused coarse histograms (LDS-aggregated). 1024-thread blocks.
__global__ void edge_hist2(const int* __restrict__ ei,
                           uint_t* __restrict__ bhA2, uint_t* __restrict__ bhC) {
    __shared__ uint_t hA[NBKT2], hC[NBKT];
    int tid = threadIdx.x;
    for (int i = tid; i < NBKT2; i += 1024) hA[i] = 0;
    for (int i = tid; i < NBKT; i += 1024) hC[i] = 0;
    __syncthreads();
    for (int e = blockIdx.x * 1024 + tid; e < EE; e += 256 * 1024) {
        uint_t u = (uint_t)ei[e];
        uint_t v = (uint_t)ei[EE + e];
        atomicAdd(&hA[(u / 12500u) * 196u + (v >> 9)], 1u);
        atomicAdd(&hC[u >> 9], 1u);
    }
    __syncthreads();
    for (int i = tid; i < NBKT2; i += 1024) if (hA[i]) atomicAdd(&bhA2[i], hA[i]);
    for (int i = tid; i < NBKT; i += 1024)  if (hC[i]) atomicAdd(&bhC[i], hC[i]);
}

// Single-block exclusive scan. out[0..n] (out[n]=total), optional copy out2[0..n-1].
__global__ void scan_small(const uint_t* __restrict__ in, uint_t* __restrict__ out,
                           uint_t* __restrict__ out2, int n) {
    __shared__ uint_t part[256];
    int tid = threadIdx.x;
    int per = (n + 255) >> 8;
    int lo = tid * per;
    int hi = lo + per; if (hi > n) hi = n;
    if (lo > n) lo = n;
    uint_t s = 0;
    for (int i = lo; i < hi; ++i) s += in[i];
    part[tid] = s;
    __syncthreads();
    for (int off = 1; off < 256; off <<= 1) {
        uint_t v = (tid >= off) ? part[tid - off] : 0u;
        __syncthreads();
        part[tid] += v;
        __syncthreads();
    }
    uint_t run = part[tid] - s;
    for (int i = lo; i < hi; ++i) {
        out[i] = run;
        if (out2) out2[i] = run;
        run += in[i];
    }
    if (tid == 255) out[n] = run;
}

#define TPB 4096
#define CCAP 1536   // per-(block,slice) staging cap: Binomial(4096,1/8) mean 512, sigma 21 -> +48 sigma
// K2b (XCD-OWNED write fronts, round 15): grid = tiles x 8 slices; block (t,s)
// (s = blockIdx&7 -> XCD s) reads tile t once but scatters ONLY edges it owns:
// A-side if u/12500==s (A-buckets s*196+q advanced only by XCD-s blocks), C-side
// if (u>>9)&7==s (C-bucket b owned by XCD b%8). Round-14 counters: shared fronts
// across 8 non-coherent L2s gave 1.9x write amplification (60.8 MB for ~32 MB) and
// cross-XCD line ping-pong (VALU 4%, latency-bound). Fronts now accumulate full
// lines in the owning XCD's L2. 8x tile re-read is L3-absorbed (ei = 12.8 MB).
__global__ void bucket_place_AC(const int* __restrict__ ei, const float* __restrict__ ea,
                                uint_t* __restrict__ bcurA, uint_t* __restrict__ bcurC,
                                uint4* __restrict__ pk4, uint_t* __restrict__ pkC) {
    __shared__ uint_t histA[NBKT], gbaseA[NBKT], curA[NBKT];
    __shared__ uint_t histC[NBKT], lbaseC[NBKT], gbaseC[NBKT], curC[NBKT];
    __shared__ uint_t pkst[CCAP];        // owned C-keys
    __shared__ uint_t gpk[CCAP];         // bucket-reordered C-keys
    __shared__ uint2  ast[CCAP];         // owned A-edges: {q<<24 | cl<<17 | u, e}
    __shared__ uint_t part[1024];
    __shared__ uint_t nA, nC;
    int tid = threadIdx.x;
    uint_t s = (uint_t)(blockIdx.x & 7);
    int t0 = (blockIdx.x >> 3) * TPB;
    int nt = EE - t0; if (nt > TPB) nt = TPB;
    for (int i = tid; i < NBKT; i += 1024) { histA[i] = 0; curA[i] = 0; histC[i] = 0; curC[i] = 0; }
    if (tid == 0) { nA = 0; nC = 0; }
    __syncthreads();
    for (int i = tid; i < nt; i += 1024) {
        int e = t0 + i;
        uint_t u = (uint_t)ei[e];
        uint_t v = (uint_t)ei[EE + e];
        if (u / 12500u == s) {
            uint_t q = v >> 9;
            atomicAdd(&histA[q], 1u);
            uint_t k = atomicAdd(&nA, 1u);
            if (k < CCAP) { ast[k].x = (q << 24) | (((v >> 2) & 127u) << 17) | u; ast[k].y = (uint_t)e; }
        }
        uint_t cb = u >> 9;
        if ((cb & 7u) == s) {
            atomicAdd(&histC[cb], 1u);
            uint_t k = atomicAdd(&nC, 1u);
            if (k < CCAP) pkst[k] = ((u >> 2) << 15) | (v >> 2);
        }
    }
    __syncthreads();
    // reserve global runs (A-fronts slice-local; C-fronts owned by XCD b%8)
    for (int b = tid; b < NBKT; b += 1024) {
        uint_t h = histA[b];
        if (h) gbaseA[b] = atomicAdd(&bcurA[s * 196u + (uint_t)b], h);
        uint_t hc = histC[b];
        if (hc) gbaseC[b] = atomicAdd(&bcurC[b], hc);
    }
    uint_t h = (tid < NBKT) ? histC[tid] : 0u;
    part[tid] = h;
    __syncthreads();
    for (int off = 1; off < 1024; off <<= 1) {
        uint_t v = (tid >= off) ? part[tid - off] : 0u;
        __syncthreads();
        part[tid] += v;
        __syncthreads();
    }
    if (tid < NBKT) lbaseC[tid] = part[tid] - h;
    __syncthreads();
    uint_t mC = nC; if (mC > CCAP) mC = CCAP;
    uint_t mA = nA; if (mA > CCAP) mA = CCAP;
    // C-side LDS reorder, then grouped global write (runs ~84 B, XCD-local fronts)
    for (uint_t k = tid; k < mC; k += 1024u) {
        uint_t w = pkst[k];
        uint_t b = w >> 22;
        uint_t r = lbaseC[b] + atomicAdd(&curC[b], 1u);
        gpk[r] = w;
    }
    __syncthreads();
    for (uint_t r = tid; r < mC; r += 1024u) {
        uint_t w = gpk[r];
        uint_t b = w >> 22;
        pkC[gbaseC[b] + (r - lbaseC[b])] = w;
    }
    // A-side scatter from staged ids (ea gathered 12 B/edge; lines L3-shared)
    for (uint_t k = tid; k < mA; k += 1024u) {
        uint2 a = ast[k];
        uint_t q = a.x >> 24;
        uint_t r = gbaseA[q] + atomicAdd(&curA[q], 1u);
        uint4 p;
        p.x = a.x & 0xFFFFFFu;
        p.y = __float_as_uint(ea[(size_t)a.y * 3 + 0]);
        p.z = __float_as_uint(ea[(size_t)a.y * 3 + 1]);
        p.w = __float_as_uint(ea[(size_t)a.y * 3 + 2]);
        pk4[r] = p;
    }
}

// K2c: in-LDS counting sort of each (slice, dst-coarse) bucket by cluster-local id;
// sorted KEYS (.x) written to pkW. ea sums per cluster via LDS FLOAT ATOMICS keyed
// by the cluster id in the key (order-independent — round-8's sorted-range read of
// unsorted st[] was the absmax=41.9 bug).
__global__ void bucket_sort_A2(const uint_t* __restrict__ bbA2, const uint4* __restrict__ pk4,
                               uint_t* __restrict__ pkW, uint_t* __restrict__ paggw,
                               uint_t* __restrict__ offs2) {
    __shared__ uint4 st[2048];                      // 32 KB payload staging
    __shared__ uint_t hist[128], base2[128], cur[128];
    __shared__ float eacc0[128], eacc1[128], eacc2[128];
    __shared__ uint_t part[256];
    int tid = threadIdx.x, bk = blockIdx.x;
    uint_t s = bbA2[bk], epos = bbA2[bk + 1];
    int n = (int)(epos - s);
    if (n > 2048) n = 2048;   // statistically unreachable; guards LDS bounds
    if (tid < 128) {
        hist[tid] = 0; cur[tid] = 0;
        eacc0[tid] = 0.f; eacc1[tid] = 0.f; eacc2[tid] = 0.f;
    }
    for (int i = tid; i < n; i += 256) st[i] = pk4[s + i];
    __syncthreads();
    for (int i = tid; i < n; i += 256) {
        uint4 p = st[i];
        uint_t d = p.x >> 17;
        atomicAdd(&hist[d], 1u);
        atomicAdd(&eacc0[d], __uint_as_float(p.y));
        atomicAdd(&eacc1[d], __uint_as_float(p.z));
        atomicAdd(&eacc2[d], __uint_as_float(p.w));
    }
    __syncthreads();
    uint_t h = (tid < 128) ? hist[tid] : 0u;
    part[tid] = h;
    __syncthreads();
    for (int off = 1; off < 256; off <<= 1) {
        uint_t v = (tid >= off) ? part[tid - off] : 0u;
        __syncthreads();
        part[tid] += v;
        __syncthreads();
    }
    int sl = bk / 196, q = bk - sl * 196;
    if (tid < 128) {
        base2[tid] = part[tid] - h;
        int c = q * 128 + tid;
        if (c < CC) {
            uint_t kk = (uint_t)sl * CC + (uint_t)c;
            offs2[kk] = s + base2[tid];
            paggw[(size_t)kk * 66 + 64] = f2bf(eacc0[tid]) | (f2bf(eacc1[tid]) << 16);
            paggw[(size_t)kk * 66 + 65] = f2bf(eacc2[tid]);   // slot 131 = 0
        }
    }
    if (bk == 0 && tid == 0) offs2[8 * CC] = EE;
    __syncthreads();
    for (int i = tid; i < n; i += 256) {
        uint4 p = st[i];
        uint_t d = p.x >> 17;
        uint_t r = base2[d] + atomicAdd(&cur[d], 1u);
        pkW[s + r] = p.x & 0x1FFFFu ? p.x : p.x;   // (no-op form avoided below)
    }
}

// K2c': counting-sort each C-bucket by 5-bit sub key ((u>>2)&31), in place, so the
// dedupe kernels read ONLY their own ~256-entry segment.
__global__ void bucket_sort_C(const uint_t* __restrict__ bbC, uint_t* __restrict__ pkC,
                              uint_t* __restrict__ csub) {
    __shared__ uint_t st[8960];                     // 35.8 KB (bucket mean 8192, +8.5 sigma)
    __shared__ uint_t hist[32], base2[32], cur[32];
    __shared__ uint_t part[256];
    int tid = threadIdx.x, bk = blockIdx.x;
    uint_t s = bbC[bk], epos = bbC[bk + 1];
    int n = (int)(epos - s);
    if (n > 8960) n = 8960;
    if (tid < 32) { hist[tid] = 0; cur[tid] = 0; }
    for (int i = tid; i < n; i += 256) st[i] = pkC[s + i];
    __syncthreads();
    for (int i = tid; i < n; i += 256) atomicAdd(&hist[(st[i] >> 17) & 31u], 1u);
    __syncthreads();
    uint_t h = (tid < 32) ? hist[tid] : 0u;
    part[tid] = h;
    __syncthreads();
    for (int off = 1; off < 256; off <<= 1) {
        uint_t v = (tid >= off) ? part[tid - off] : 0u;
        __syncthreads();
        part[tid] += v;
        __syncthreads();
    }
    if (tid < 32) {
        base2[tid] = part[tid] - h;
        csub[bk * 32 + tid] = s + base2[tid];
    }
    if (bk == 0 && tid == 0) csub[NSEG] = EE;
    __syncthreads();
    for (int i = tid; i < n; i += 256) {
        uint_t w = st[i];
        uint_t d = (w >> 17) & 31u;
        uint_t r = base2[d] + atomicAdd(&cur[d], 1u);
        pkC[s + r] = w;
    }
}

// K3: per cluster: new_pos + new_batch straight to out (enc_emit reads out[O_POS]).
__global__ void cluster_pass(const float* __restrict__ pos, const int* __restrict__ batch,
                             float* __restrict__ out) {
    int c = blockIdx.x * 256 + threadIdx.x;
    if (c >= CC) return;
    float px = 0.f, py = 0.f, pz = 0.f;
    for (int j = 0; j < 4; ++j) {
        int n = c * 4 + j;
        px += pos[n * 3 + 0];
        py += pos[n * 3 + 1];
        pz += pos[n * 3 + 2];
    }
    px *= 0.25f; py *= 0.25f; pz *= 0.25f;
    out[O_POS + c * 3 + 0] = px;
    out[O_POS + c * 3 + 1] = py;
    out[O_POS + c * 3 + 2] = pz;
    int b = batch[c * 4];
    b = max(b, batch[c * 4 + 1]);
    b = max(b, batch[c * 4 + 2]);
    b = max(b, batch[c * 4 + 3]);
    out[O_BATCH + c] = (float)b;
}

// K2d: 8 clusters per WAVE (round-14 verified: amortizes the ~600 cy/wave fixed
// overhead 8x). One wave walks 8 consecutive clusters of its slice; inner loop =
// verified unroll-4 with batched consecutive key loads. s = blockIdx&7 pins
// x-slice s (3.2 MB) to one XCD's L2. Empty clusters still write zero rows.
#define CPW 8
__global__ void cluster_reduce5(const uint_t* __restrict__ offs2, const uint_t* __restrict__ pkW,
                                const uint_t* __restrict__ xb, uint_t* __restrict__ paggw) {
    int tid = threadIdx.x;
    int lane = tid & 63;
    int s = blockIdx.x & 7;
    int c0 = ((blockIdx.x >> 3) * 4 + (tid >> 6)) * CPW;   // 4 waves/block
    if (c0 >= CC) return;
    uint_t kk0 = (uint_t)s * CC + (uint_t)c0;
    const uint_t* xl = xb + lane;
    for (int cl = 0; cl < CPW; ++cl) {
        if (c0 + cl >= CC) break;
        uint_t start = (uint_t)__builtin_amdgcn_readfirstlane((int)offs2[kk0 + cl]);
        uint_t end   = (uint_t)__builtin_amdgcn_readfirstlane((int)offs2[kk0 + cl + 1]);
        float a0 = 0.f, a1 = 0.f;
        uint_t i = start;
        for (; i + 4u <= end; i += 4u) {
            uint_t w0 = pkW[i + 0u];                // uniform, consecutive -> s_load_dwordx4
            uint_t w1 = pkW[i + 1u];
            uint_t w2 = pkW[i + 2u];
            uint_t w3 = pkW[i + 3u];
            uint_t x0 = xl[(size_t)(w0 & 0x1FFFFu) * 64u];   // 4 independent 256 B row loads
            uint_t x1 = xl[(size_t)(w1 & 0x1FFFFu) * 64u];
            uint_t x2 = xl[(size_t)(w2 & 0x1FFFFu) * 64u];
            uint_t x3 = xl[(size_t)(w3 & 0x1FFFFu) * 64u];
            a0 += bf2f((ushort_t)(x0 & 0xffffu)); a1 += bf2f((ushort_t)(x0 >> 16));
            a0 += bf2f((ushort_t)(x1 & 0xffffu)); a1 += bf2f((ushort_t)(x1 >> 16));
            a0 += bf2f((ushort_t)(x2 & 0xffffu)); a1 += bf2f((ushort_t)(x2 >> 16));
            a0 += bf2f((ushort_t)(x3 & 0xffffu)); a1 += bf2f((ushort_t)(x3 >> 16));
        }
        for (; i < end; ++i) {
            uint_t wj = pkW[i];
            uint_t xv = xl[(size_t)(wj & 0x1FFFFu) * 64u];
            a0 += bf2f((ushort_t)(xv & 0xffffu));
            a1 += bf2f((ushort_t)(xv >> 16));
        }
        paggw[(size_t)(kk0 + (uint_t)cl) * 66 + lane] = f2bf(a0) | (f2bf(a1) << 16);
    }
}

// K4: x_new[c][o] = 0.25 * sum_{j<131} (sum_s pagg[s][c][j]) * M1[j][o].
// agg_merge fused into the staging loop (slice order s=0..7 preserved).
#define GEMM_CPB 32   // clusters per block = 4 iterations of 8
__global__ void gemm_tiled(const uint_t* __restrict__ paggw, const ushort_t* __restrict__ m1b,
                           float* __restrict__ out) {
    __shared__ ushort_t m1s[131 * 128];            // 33.5 KB bf16
    __shared__ __align__(16) float srowT[132][8];  // 4.2 KB, [j][cluster-in-group]
    int tid = threadIdx.x;
    {
        const uint_t* m1w = (const uint_t*)m1b;
        uint_t* m1sw = (uint_t*)m1s;
        for (int i = tid; i < 131 * 64; i += 256) m1sw[i] = m1w[i];
    }
    int o = tid & 127, half = tid >> 7;
    int c0b = blockIdx.x * GEMM_CPB;
    for (int it = 0; it < GEMM_CPB / 8; ++it) {
        int c0 = c0b + it * 8;
        __syncthreads();   // previous-iteration readers done before overwrite
        for (int i = tid; i < 528; i += 256) {
            int cg = i / 66, rem = i - cg * 66;
            int c = c0 + cg;
            float lo = 0.f, hi = 0.f;
            if (c < CC) {
                #pragma unroll
                for (int s = 0; s < 8; ++s) {
                    uint_t w = paggw[((size_t)s * 25000u + (uint_t)c) * 66 + rem];
                    lo += bf2f((ushort_t)(w & 0xffffu));
                    hi += bf2f((ushort_t)(w >> 16));
                }
            }
            srowT[rem * 2][cg]     = lo;
            srowT[rem * 2 + 1][cg] = hi;
        }
        __syncthreads();   // also covers m1s staging on it==0
        float acc0 = 0.f, acc1 = 0.f, acc2 = 0.f, acc3 = 0.f;
        #pragma unroll 4
        for (int j = 0; j < 131; ++j) {
            float m = bf2f(m1s[j * 128 + o]);
            float4 s = *(const float4*)&srowT[j][half * 4];  // broadcast within wave
            acc0 += s.x * m;
            acc1 += s.y * m;
            acc2 += s.z * m;
            acc3 += s.w * m;
        }
        int cb = c0 + half * 4;
        if (cb + 0 < CC) out[O_XNEW + (size_t)(cb + 0) * 128 + o] = 0.25f * acc0;
        if (cb + 1 < CC) out[O_XNEW + (size_t)(cb + 1) * 128 + o] = 0.25f * acc1;
        if (cb + 2 < CC) out[O_XNEW + (size_t)(cb + 2) * 128 + o] = 0.25f * acc2;
        if (cb + 3 < CC) out[O_XNEW + (size_t)(cb + 3) * 128 + o] = 0.25f * acc3;
    }
}

// K6a: per-segment dedupe: read OWN ~256-entry segment, 12.5 KB LDS bitmap
// (4 u-clusters x 25000 v bits), block scan, emit deduped keys (le, rank-dense)
// to kbuf[bid*KCAP] + count. Bitmap built ONCE (emit kernel reads keys, not pkC).
__global__ void enc_count(const uint_t* __restrict__ csub, const uint_t* __restrict__ pkC,
                          uint_t* __restrict__ bcnt, uint_t* __restrict__ kbuf) {
    __shared__ uint_t bmp[3125];
    __shared__ uint_t sh[256];
    int tid = threadIdx.x, bid = blockIdx.x;
    uint_t s = csub[bid], epos = csub[bid + 1];
    int n = (int)(epos - s);
    for (int i = tid; i < 3125; i += 256) bmp[i] = 0;
    __syncthreads();
    for (int i = tid; i < n; i += 256) {
        uint_t w = pkC[s + i];
        uint_t le = ((w >> 15) & 3u) * 25000u + (w & 32767u);
        atomicOr(&bmp[le >> 5], 1u << (le & 31u));
    }
    __syncthreads();
    int lo = tid * 13, hi = lo + 13;
    if (lo > 3125) lo = 3125;
    if (hi > 3125) hi = 3125;
    uint_t mine = 0;
    for (int i = lo; i < hi; ++i) mine += __popc(bmp[i]);
    sh[tid] = mine;
    __syncthreads();
    for (int off = 1; off < 256; off <<= 1) {
        uint_t v = (tid >= off) ? sh[tid - off] : 0u;
        __syncthreads();
        sh[tid] += v;
        __syncthreads();
    }
    uint_t r = sh[tid] - mine;
    uint_t kb = (uint_t)bid * KCAP;
    for (int i = lo; i < hi; ++i) {
        uint_t bits = bmp[i];
        while (bits) {
            int b = __builtin_ctz(bits);
            bits &= bits - 1u;
            if (r < KCAP) kbuf[kb + r] = (uint_t)i * 32u + (uint_t)b;
            r++;
        }
    }
    if (tid == 255) bcnt[bid] = min(sh[255], (uint_t)KCAP);
}

// K6t: zero only the unwritten tails of EI/ATTR (the full 32 MB memset was ~99.7%
// wasted — emit covers ranks [0,total)).
__global__ void tail_zero(const uint_t* __restrict__ ebase, float* __restrict__ out) {
    uint_t total = ebase[NSEG];
    uint_t idx = blockIdx.x * 256u + (uint_t)threadIdx.x;
    uint_t stride = gridDim.x * 256u;
    for (uint_t k = total + idx; k < EE; k += stride) {
        out[O_EI + k] = 0.f;
        out[O_EI + EE + k] = 0.f;
    }
    for (uint_t k = 3u * total + idx; k < 3u * EE; k += stride) {
        out[O_ATTR + k] = 0.f;
    }
}

// K6b: decode dense keys, write u/v COALESCED + attrs (np gathers are L2-resident).
// Global order: bid asc (= u-group asc), key asc within (= (u&3, v) asc) ->
// ascending enc, identical to jnp.unique output order.
__global__ void enc_emit(const uint_t* __restrict__ ebase, const uint_t* __restrict__ kbuf,
                         float* __restrict__ out) {
    int tid = threadIdx.x, bid = blockIdx.x;
    uint_t g0 = ebase[bid], g1 = ebase[bid + 1];
    int cnt = (int)(g1 - g0);
    const float* np = out + O_POS;
    uint_t ubase = ((uint_t)(bid >> 5)) * 128u + ((uint_t)(bid & 31)) * 4u;
    uint_t kb = (uint_t)bid * KCAP;
    for (int r = tid; r < cnt; r += 256) {
        uint_t le = kbuf[kb + r];
        uint_t uo = le / 25000u;
        uint_t v = le - uo * 25000u;
        uint_t u = ubase + uo;
        uint_t rank = g0 + (uint_t)r;
        out[O_EI + rank] = (float)u;
        out[O_EI + EE + rank] = (float)v;
        out[O_ATTR + (size_t)rank * 3 + 0] = np[v * 3 + 0] - np[u * 3 + 0];
        out[O_ATTR + (size_t)rank * 3 + 1] = np[v * 3 + 1] - np[u * 3 + 1];
        out[O_ATTR + (size_t)rank * 3 + 2] = np[v * 3 + 2] - np[u * 3 + 2];
    }
}

extern "C" void kernel_launch(void* const* d_in, const int* in_sizes, int n_in,
                              void* d_out, int out_size, void* d_ws, size_t ws_size,
                              hipStream_t stream) {
    const float* x     = (const float*)d_in[0];
    const float* pos   = (const float*)d_in[1];
    const int*   ei    = (const int*)d_in[2];
    const float* ea    = (const float*)d_in[3];
    const int*   batch = (const int*)d_in[4];
    const float* Wconv = (const float*)d_in[5];
    const float* Wedge = (const float*)d_in[6];
    // d_in[7] = D_bloom: dead (bloom_pos never reaches an output)
    const float* Wg    = (const float*)d_in[8];
    // d_in[9] = W_gattr: contribution cancels exactly within each cluster

    float*  out = (float*)d_out;
    uint_t* ws  = (uint_t*)d_ws;

    if (ws_size < (size_t)WS_WORDS * 4) return;

    ushort_t* m1b    = (ushort_t*)(ws + W_M1B);
    uint_t*   pkW    = ws + W_AGGB;             // sorted keys
    uint_t*   paggw  = ws + W_PAGG;
    uint4*    pk4    = (uint4*)(ws + W_PKA4);
    uint_t*   pkC    = ws + W_PKC;
    uint_t*   offs2  = ws + W_OFFS2;
    uint_t*   bhA2   = ws + W_BHA2;
    uint_t*   bhC    = ws + W_BHC;
    uint_t*   bbA2   = ws + W_BBA2;
    uint_t*   bcurA2 = ws + W_BCURA2;
    uint_t*   bbC    = ws + W_BBC;
    uint_t*   bcurC  = ws + W_BCURC;
    uint_t*   xb     = (uint_t*)(out + O_EI);   // 6.4M-word bf16-x staging in out region
    // dead-region reuse (valid after bucket_sort_A2 / gemm_tiled):
    uint_t*   csub   = ws + W_PKA4;             // u32 [NSEG+1]
    uint_t*   bcnt2  = ws + W_PKA4 + 8192u;     // u32 [NSEG]
    uint_t*   ebase2 = ws + W_PKA4 + 16384u;    // u32 [NSEG+1]
    uint_t*   kbuf   = ws + W_PAGG;             // u32 [NSEG*KCAP] = 6.42M <= 13.2M

    hipMemsetAsync(bhA2, 0, (size_t)(NBKT2 + NBKT) * 4, stream);   // bhA2 + bhC contiguous

    xpack<<<dim3(12500), dim3(256), 0, stream>>>((const float4*)x, (uint2*)xb);
    build_m1f<<<dim3(131), dim3(128), 0, stream>>>(Wconv, Wedge, Wg, m1b);
    edge_hist2<<<dim3(256), dim3(1024), 0, stream>>>(ei, bhA2, bhC);
    scan_small<<<dim3(1), dim3(256), 0, stream>>>(bhA2, bbA2, bcurA2, NBKT2);
    scan_small<<<dim3(1), dim3(256), 0, stream>>>(bhC, bbC, bcurC, NBKT);
    bucket_place_AC<<<dim3(((EE + TPB - 1) / TPB) * 8), dim3(1024), 0, stream>>>(ei, ea, bcurA2, bcurC, pk4, pkC);
    bucket_sort_A2<<<dim3(NBKT2), dim3(256), 0, stream>>>(bbA2, pk4, pkW, paggw, offs2);
    cluster_pass<<<dim3(98), dim3(256), 0, stream>>>(pos, batch, out);
    cluster_reduce5<<<dim3(((CC + 4 * CPW - 1) / (4 * CPW)) * 8), dim3(256), 0, stream>>>(offs2, pkW, xb, paggw);
    gemm_tiled<<<dim3((CC + GEMM_CPB - 1) / GEMM_CPB), dim3(256), 0, stream>>>(paggw, m1b, out);
    bucket_sort_C<<<dim3(NBKT), dim3(256), 0, stream>>>(bbC, pkC, csub);
    enc_count<<<dim3(NSEG), dim3(256), 0, stream>>>(csub, pkC, bcnt2, kbuf);
    scan_small<<<dim3(1), dim3(256), 0, stream>>>(bcnt2, ebase2, (uint_t*)0, NSEG);
    tail_zero<<<dim3(512), dim3(256), 0, stream>>>(ebase2, out);
    enc_emit<<<dim3(NSEG), dim3(256), 0, stream>>>(ebase2, kbuf, out);
}

// Round 16
// 421.969 us; speedup vs baseline: 1.0836x; 1.0836x over previous
//
#include <hip/hip_runtime.h>
#include <hip/hip_bf16.h>
#include <stdint.h>

typedef unsigned int uint_t;
typedef unsigned short ushort_t;

#define NN 100000
#define EE 1600000
#define CC 25000
#define DINTER 144
#define NBKT 196          // C-side coarse buckets: src cluster >> 7
#define NBKT2 1568        // A-side buckets: (src_node/12500)*196 + (dst_node>>9)
#define NSEG 6272         // dedupe segments: 196 buckets * 32 subs (4 u-clusters each)
#define KCAP 1024         // keys per segment cap (mean 256, sigma 16 -> +48 sigma)

// ---- ws layout in 32-bit words (total 92.27 MB, proven) ----
#define W_M1B      0u         // u16 [131*128] bf16 m1 = 8384 words
#define W_AGGB     8384u      // pkW sorted keys region (u32 [1,600,000] fits in 1,650,000)
#define W_PAGG     1658384u   // bf16[8][25000*132] = 13,200,000 words (kbuf reuse after gemm)
#define W_PKA4     14858384u  // uint4[1,600,000] = 6,400,000 words (csub/bcnt/ebase reuse after sort)
#define W_PKC      21258384u  // u32 [1600000]
#define W_OFFS2    22858384u  // u32 [200001]  per-(slice,cluster) segment offsets
#define W_BHA2     23058385u  // u32 [1568]
#define W_BHC      23059953u  // u32 [196]   (adjacent to BHA2: one memset of 1764)
#define W_BBA2     23060149u  // u32 [1569]
#define W_BCURA2   23061718u  // u32 [1568]
#define W_BBC      23063286u  // u32 [197]
#define W_BCURC    23063483u  // u32 [196]
#define WS_WORDS   23066816u

// ---- out layout in FLOAT32 elements (total 11,300,000) ----
#define O_XNEW  0u
#define O_POS   3200000u
#define O_EI    3275000u
#define O_ATTR  6475000u
#define O_BATCH 11275000u
// x_bf16 staging: first 6.4M words of the O_EI region (tails zeroed by tail_zero)
// new_pos f32[25000*3] lives at out[O_POS] and is read back by enc_emit.

static __device__ __forceinline__ uint_t f2bf(float f) {
    union { float f; uint_t i; } v; v.f = f;
    uint_t x = v.i;
    return (x + 0x7fffu + ((x >> 16) & 1u)) >> 16;  // RNE
}
static __device__ __forceinline__ float bf2f(ushort_t u) {
    union { uint_t i; float f; } v; v.i = ((uint_t)u) << 16; return v.f;
}

// K0: pack x (f32) -> bf16x2 words into the output-staging region.
__global__ void xpack(const float4* __restrict__ x4, uint2* __restrict__ xb2) {
    int i = blockIdx.x * 256 + threadIdx.x;
    if (i >= NN * 32) return;            // 12.8M floats / 4
    float4 v = x4[i];
    uint2 r;
    r.x = f2bf(v.x) | (f2bf(v.y) << 16);
    r.y = f2bf(v.z) | (f2bf(v.w) << 16);
    xb2[i] = r;
}

// K1: M1[j][o] = sum_f Wrow_j[f] * Wg[f][o], emitted directly as bf16.
__global__ void build_m1f(const float* __restrict__ Wconv,
                          const float* __restrict__ Wedge,
                          const float* __restrict__ Wg,
                          ushort_t* __restrict__ m1b) {
    int j = blockIdx.x;   // 0..130
    int o = threadIdx.x;  // 0..127
    const float* wrow = (j < 128) ? (Wconv + j * DINTER + 16)
                                  : (Wedge + (j - 128) * DINTER + 16);
    float acc = 0.f;
    for (int f = 0; f < 128; ++f)
        acc += wrow[f] * Wg[f * 128 + o];
    m1b[j * 128 + o] = (ushort_t)f2bf(acc);
}

// K2a: fused coarse histograms (LDS-aggregated). 1024-thread blocks.
__global__ void edge_hist2(const int* __restrict__ ei,
                           uint_t* __restrict__ bhA2, uint_t* __restrict__ bhC) {
    __shared__ uint_t hA[NBKT2], hC[NBKT];
    int tid = threadIdx.x;
    for (int i = tid; i < NBKT2; i += 1024) hA[i] = 0;
    for (int i = tid; i < NBKT; i += 1024) hC[i] = 0;
    __syncthreads();
    for (int e = blockIdx.x * 1024 + tid; e < EE; e += 256 * 1024) {
        uint_t u = (uint_t)ei[e];
        uint_t v = (uint_t)ei[EE + e];
        atomicAdd(&hA[(u / 12500u) * 196u + (v >> 9)], 1u);
        atomicAdd(&hC[u >> 9], 1u);
    }
    __syncthreads();
    for (int i = tid; i < NBKT2; i += 1024) if (hA[i]) atomicAdd(&bhA2[i], hA[i]);
    for (int i = tid; i < NBKT; i += 1024)  if (hC[i]) atomicAdd(&bhC[i], hC[i]);
}

// Single-block exclusive scan. out[0..n] (out[n]=total), optional copy out2[0..n-1].
__global__ void scan_small(const uint_t* __restrict__ in, uint_t* __restrict__ out,
                           uint_t* __restrict__ out2, int n) {
    __shared__ uint_t part[256];
    int tid = threadIdx.x;
    int per = (n + 255) >> 8;
    int lo = tid * per;
    int hi = lo + per; if (hi > n) hi = n;
    if (lo > n) lo = n;
    uint_t s = 0;
    for (int i = lo; i < hi; ++i) s += in[i];
    part[tid] = s;
    __syncthreads();
    for (int off = 1; off < 256; off <<= 1) {
        uint_t v = (tid >= off) ? part[tid - off] : 0u;
        __syncthreads();
        part[tid] += v;
        __syncthreads();
    }
    uint_t run = part[tid] - s;
    for (int i = lo; i < hi; ++i) {
        out[i] = run;
        if (out2) out2[i] = run;
        run += in[i];
    }
    if (tid == 255) out[n] = run;
}

#define TPB 4096
// K2b (round 16 = round-14 shared fronts REVERT + LDS-key A-pass): round-15's
// XCD-owned fronts halved WRITE (60.8->36.7 MB) but the 8x tile re-read blew up
// FETCH (20.6->108.5 MB) -> net 64->91 us regression. Reverted. NEW: the A-side
// scatter no longer re-reads ei — u is reconstructed from pkst[] + a 4 KB lo2[]
// (u&3) array, deleting ~3.2M dependent L2 loads from the latency-bound pass.
__global__ void bucket_place_AC(const int* __restrict__ ei, const float* __restrict__ ea,
                                uint_t* __restrict__ bcurA, uint_t* __restrict__ bcurC,
                                uint4* __restrict__ pk4, uint_t* __restrict__ pkC) {
    __shared__ uint_t histA[NBKT2], gbaseA[NBKT2], curA[NBKT2];   // 18.8 KB
    __shared__ uint_t pkst[TPB];                                  // 16 KB C-keys
    __shared__ uint_t gpk[TPB];                                   // 16 KB reordered
    __shared__ unsigned char lo2[TPB];                            // 4 KB u&3
    __shared__ uint_t histC[NBKT], lbaseC[NBKT], gbaseC[NBKT], curC[NBKT];
    __shared__ uint_t part[1024];
    int tid = threadIdx.x;
    int t0 = blockIdx.x * TPB;
    int nt = EE - t0; if (nt > TPB) nt = TPB;
    for (int i = tid; i < NBKT2; i += 1024) { histA[i] = 0; curA[i] = 0; }
    for (int i = tid; i < NBKT; i += 1024) { histC[i] = 0; curC[i] = 0; }
    __syncthreads();
    for (int i = tid; i < nt; i += 1024) {
        int e = t0 + i;
        uint_t u = (uint_t)ei[e];
        uint_t v = (uint_t)ei[EE + e];
        atomicAdd(&histA[(u / 12500u) * 196u + (v >> 9)], 1u);
        uint_t w = ((u >> 2) << 15) | (v >> 2);
        pkst[i] = w;
        lo2[i] = (unsigned char)(u & 3u);
        atomicAdd(&histC[w >> 22], 1u);
    }
    __syncthreads();
    for (int b = tid; b < NBKT2; b += 1024) {
        uint_t h = histA[b];
        if (h) gbaseA[b] = atomicAdd(&bcurA[b], h);
    }
    uint_t h = (tid < NBKT) ? histC[tid] : 0u;
    if (tid < NBKT) gbaseC[tid] = atomicAdd(&bcurC[tid], h);
    part[tid] = h;
    __syncthreads();
    for (int off = 1; off < 1024; off <<= 1) {
        uint_t v = (tid >= off) ? part[tid - off] : 0u;
        __syncthreads();
        part[tid] += v;
        __syncthreads();
    }
    if (tid < NBKT) lbaseC[tid] = part[tid] - h;
    __syncthreads();
    // C-side LDS reorder, then grouped global write
    for (int i = tid; i < nt; i += 1024) {
        uint_t w = pkst[i];
        uint_t b = w >> 22;
        uint_t r = lbaseC[b] + atomicAdd(&curC[b], 1u);
        gpk[r] = w;
    }
    __syncthreads();
    for (int r = tid; r < nt; r += 1024) {
        uint_t w = gpk[r];
        uint_t b = w >> 22;
        pkC[gbaseC[b] + ((uint_t)r - lbaseC[b])] = w;
    }
    // A-side scatter from LDS keys (no ei re-read); ea gathered 12 B/edge (L2/L3)
    for (int i = tid; i < nt; i += 1024) {
        int e = t0 + i;
        uint_t w = pkst[i];
        uint_t u = ((w >> 15) << 2) | (uint_t)lo2[i];
        uint_t vq = w & 32767u;                  // v >> 2
        uint_t b = (u / 12500u) * 196u + (vq >> 7);
        uint_t r = gbaseA[b] + atomicAdd(&curA[b], 1u);
        uint4 p;
        p.x = ((vq & 127u) << 17) | u;
        p.y = __float_as_uint(ea[(size_t)e * 3 + 0]);
        p.z = __float_as_uint(ea[(size_t)e * 3 + 1]);
        p.w = __float_as_uint(ea[(size_t)e * 3 + 2]);
        pk4[r] = p;
    }
}

// K2c: in-LDS counting sort of each (slice, dst-coarse) bucket by cluster-local id;
// sorted KEYS (.x) written to pkW. ea sums per cluster via LDS FLOAT ATOMICS keyed
// by the cluster id in the key (order-independent — round-8's sorted-range read of
// unsorted st[] was the absmax=41.9 bug).
__global__ void bucket_sort_A2(const uint_t* __restrict__ bbA2, const uint4* __restrict__ pk4,
                               uint_t* __restrict__ pkW, uint_t* __restrict__ paggw,
                               uint_t* __restrict__ offs2) {
    __shared__ uint4 st[2048];                      // 32 KB payload staging
    __shared__ uint_t hist[128], base2[128], cur[128];
    __shared__ float eacc0[128], eacc1[128], eacc2[128];
    __shared__ uint_t part[256];
    int tid = threadIdx.x, bk = blockIdx.x;
    uint_t s = bbA2[bk], epos = bbA2[bk + 1];
    int n = (int)(epos - s);
    if (n > 2048) n = 2048;   // statistically unreachable; guards LDS bounds
    if (tid < 128) {
        hist[tid] = 0; cur[tid] = 0;
        eacc0[tid] = 0.f; eacc1[tid] = 0.f; eacc2[tid] = 0.f;
    }
    for (int i = tid; i < n; i += 256) st[i] = pk4[s + i];
    __syncthreads();
    for (int i = tid; i < n; i += 256) {
        uint4 p = st[i];
        uint_t d = p.x >> 17;
        atomicAdd(&hist[d], 1u);
        atomicAdd(&eacc0[d], __uint_as_float(p.y));
        atomicAdd(&eacc1[d], __uint_as_float(p.z));
        atomicAdd(&eacc2[d], __uint_as_float(p.w));
    }
    __syncthreads();
    uint_t h = (tid < 128) ? hist[tid] : 0u;
    part[tid] = h;
    __syncthreads();
    for (int off = 1; off < 256; off <<= 1) {
        uint_t v = (tid >= off) ? part[tid - off] : 0u;
        __syncthreads();
        part[tid] += v;
        __syncthreads();
    }
    int sl = bk / 196, q = bk - sl * 196;
    if (tid < 128) {
        base2[tid] = part[tid] - h;
        int c = q * 128 + tid;
        if (c < CC) {
            uint_t kk = (uint_t)sl * CC + (uint_t)c;
            offs2[kk] = s + base2[tid];
            paggw[(size_t)kk * 66 + 64] = f2bf(eacc0[tid]) | (f2bf(eacc1[tid]) << 16);
            paggw[(size_t)kk * 66 + 65] = f2bf(eacc2[tid]);   // slot 131 = 0
        }
    }
    if (bk == 0 && tid == 0) offs2[8 * CC] = EE;
    __syncthreads();
    for (int i = tid; i < n; i += 256) {
        uint4 p = st[i];
        uint_t d = p.x >> 17;
        uint_t r = base2[d] + atomicAdd(&cur[d], 1u);
        pkW[s + r] = p.x;
    }
}

// K2c': counting-sort each C-bucket by 5-bit sub key ((u>>2)&31), in place, so the
// dedupe kernels read ONLY their own ~256-entry segment.
__global__ void bucket_sort_C(const uint_t* __restrict__ bbC, uint_t* __restrict__ pkC,
                              uint_t* __restrict__ csub) {
    __shared__ uint_t st[8960];                     // 35.8 KB (bucket mean 8192, +8.5 sigma)
    __shared__ uint_t hist[32], base2[32], cur[32];
    __shared__ uint_t part[256];
    int tid = threadIdx.x, bk = blockIdx.x;
    uint_t s = bbC[bk], epos = bbC[bk + 1];
    int n = (int)(epos - s);
    if (n > 8960) n = 8960;
    if (tid < 32) { hist[tid] = 0; cur[tid] = 0; }
    for (int i = tid; i < n; i += 256) st[i] = pkC[s + i];
    __syncthreads();
    for (int i = tid; i < n; i += 256) atomicAdd(&hist[(st[i] >> 17) & 31u], 1u);
    __syncthreads();
    uint_t h = (tid < 32) ? hist[tid] : 0u;
    part[tid] = h;
    __syncthreads();
    for (int off = 1; off < 256; off <<= 1) {
        uint_t v = (tid >= off) ? part[tid - off] : 0u;
        __syncthreads();
        part[tid] += v;
        __syncthreads();
    }
    if (tid < 32) {
        base2[tid] = part[tid] - h;
        csub[bk * 32 + tid] = s + base2[tid];
    }
    if (bk == 0 && tid == 0) csub[NSEG] = EE;
    __syncthreads();
    for (int i = tid; i < n; i += 256) {
        uint_t w = st[i];
        uint_t d = (w >> 17) & 31u;
        uint_t r = base2[d] + atomicAdd(&cur[d], 1u);
        pkC[s + r] = w;
    }
}

// K3: per cluster: new_pos + new_batch straight to out (enc_emit reads out[O_POS]).
__global__ void cluster_pass(const float* __restrict__ pos, const int* __restrict__ batch,
                             float* __restrict__ out) {
    int c = blockIdx.x * 256 + threadIdx.x;
    if (c >= CC) return;
    float px = 0.f, py = 0.f, pz = 0.f;
    for (int j = 0; j < 4; ++j) {
        int n = c * 4 + j;
        px += pos[n * 3 + 0];
        py += pos[n * 3 + 1];
        pz += pos[n * 3 + 2];
    }
    px *= 0.25f; py *= 0.25f; pz *= 0.25f;
    out[O_POS + c * 3 + 0] = px;
    out[O_POS + c * 3 + 1] = py;
    out[O_POS + c * 3 + 2] = pz;
    int b = batch[c * 4];
    b = max(b, batch[c * 4 + 1]);
    b = max(b, batch[c * 4 + 2]);
    b = max(b, batch[c * 4 + 3]);
    out[O_BATCH + c] = (float)b;
}

// K2d: 8 clusters per WAVE (round-14 verified). One wave walks 8 consecutive
// clusters of its slice; inner loop = verified unroll-4 with batched consecutive
// key loads. s = blockIdx&7 pins x-slice s (3.2 MB) to one XCD's L2.
#define CPW 8
__global__ void cluster_reduce5(const uint_t* __restrict__ offs2, const uint_t* __restrict__ pkW,
                                const uint_t* __restrict__ xb, uint_t* __restrict__ paggw) {
    int tid = threadIdx.x;
    int lane = tid & 63;
    int s = blockIdx.x & 7;
    int c0 = ((blockIdx.x >> 3) * 4 + (tid >> 6)) * CPW;   // 4 waves/block
    if (c0 >= CC) return;
    uint_t kk0 = (uint_t)s * CC + (uint_t)c0;
    const uint_t* xl = xb + lane;
    for (int cl = 0; cl < CPW; ++cl) {
        if (c0 + cl >= CC) break;
        uint_t start = (uint_t)__builtin_amdgcn_readfirstlane((int)offs2[kk0 + cl]);
        uint_t end   = (uint_t)__builtin_amdgcn_readfirstlane((int)offs2[kk0 + cl + 1]);
        float a0 = 0.f, a1 = 0.f;
        uint_t i = start;
        for (; i + 4u <= end; i += 4u) {
            uint_t w0 = pkW[i + 0u];                // uniform, consecutive -> s_load_dwordx4
            uint_t w1 = pkW[i + 1u];
            uint_t w2 = pkW[i + 2u];
            uint_t w3 = pkW[i + 3u];
            uint_t x0 = xl[(size_t)(w0 & 0x1FFFFu) * 64u];   // 4 independent 256 B row loads
            uint_t x1 = xl[(size_t)(w1 & 0x1FFFFu) * 64u];
            uint_t x2 = xl[(size_t)(w2 & 0x1FFFFu) * 64u];
            uint_t x3 = xl[(size_t)(w3 & 0x1FFFFu) * 64u];
            a0 += bf2f((ushort_t)(x0 & 0xffffu)); a1 += bf2f((ushort_t)(x0 >> 16));
            a0 += bf2f((ushort_t)(x1 & 0xffffu)); a1 += bf2f((ushort_t)(x1 >> 16));
            a0 += bf2f((ushort_t)(x2 & 0xffffu)); a1 += bf2f((ushort_t)(x2 >> 16));
            a0 += bf2f((ushort_t)(x3 & 0xffffu)); a1 += bf2f((ushort_t)(x3 >> 16));
        }
        for (; i < end; ++i) {
            uint_t wj = pkW[i];
            uint_t xv = xl[(size_t)(wj & 0x1FFFFu) * 64u];
            a0 += bf2f((ushort_t)(xv & 0xffffu));
            a1 += bf2f((ushort_t)(xv >> 16));
        }
        paggw[(size_t)(kk0 + (uint_t)cl) * 66 + lane] = f2bf(a0) | (f2bf(a1) << 16);
    }
}

// K4: x_new[c][o] = 0.25 * sum_{j<131} (sum_s pagg[s][c][j]) * M1[j][o].
// agg_merge fused into the staging loop (slice order s=0..7 preserved).
#define GEMM_CPB 32   // clusters per block = 4 iterations of 8
__global__ void gemm_tiled(const uint_t* __restrict__ paggw, const ushort_t* __restrict__ m1b,
                           float* __restrict__ out) {
    __shared__ ushort_t m1s[131 * 128];            // 33.5 KB bf16
    __shared__ __align__(16) float srowT[132][8];  // 4.2 KB, [j][cluster-in-group]
    int tid = threadIdx.x;
    {
        const uint_t* m1w = (const uint_t*)m1b;
        uint_t* m1sw = (uint_t*)m1s;
        for (int i = tid; i < 131 * 64; i += 256) m1sw[i] = m1w[i];
    }
    int o = tid & 127, half = tid >> 7;
    int c0b = blockIdx.x * GEMM_CPB;
    for (int it = 0; it < GEMM_CPB / 8; ++it) {
        int c0 = c0b + it * 8;
        __syncthreads();   // previous-iteration readers done before overwrite
        for (int i = tid; i < 528; i += 256) {
            int cg = i / 66, rem = i - cg * 66;
            int c = c0 + cg;
            float lo = 0.f, hi = 0.f;
            if (c < CC) {
                #pragma unroll
                for (int s = 0; s < 8; ++s) {
                    uint_t w = paggw[((size_t)s * 25000u + (uint_t)c) * 66 + rem];
                    lo += bf2f((ushort_t)(w & 0xffffu));
                    hi += bf2f((ushort_t)(w >> 16));
                }
            }
            srowT[rem * 2][cg]     = lo;
            srowT[rem * 2 + 1][cg] = hi;
        }
        __syncthreads();   // also covers m1s staging on it==0
        float acc0 = 0.f, acc1 = 0.f, acc2 = 0.f, acc3 = 0.f;
        #pragma unroll 4
        for (int j = 0; j < 131; ++j) {
            float m = bf2f(m1s[j * 128 + o]);
            float4 s = *(const float4*)&srowT[j][half * 4];  // broadcast within wave
            acc0 += s.x * m;
            acc1 += s.y * m;
            acc2 += s.z * m;
            acc3 += s.w * m;
        }
        int cb = c0 + half * 4;
        if (cb + 0 < CC) out[O_XNEW + (size_t)(cb + 0) * 128 + o] = 0.25f * acc0;
        if (cb + 1 < CC) out[O_XNEW + (size_t)(cb + 1) * 128 + o] = 0.25f * acc1;
        if (cb + 2 < CC) out[O_XNEW + (size_t)(cb + 2) * 128 + o] = 0.25f * acc2;
        if (cb + 3 < CC) out[O_XNEW + (size_t)(cb + 3) * 128 + o] = 0.25f * acc3;
    }
}

// K6a: per-segment dedupe: read OWN ~256-entry segment, 12.5 KB LDS bitmap
// (4 u-clusters x 25000 v bits), block scan, emit deduped keys (le, rank-dense)
// to kbuf[bid*KCAP] + count. Bitmap built ONCE (emit kernel reads keys, not pkC).
__global__ void enc_count(const uint_t* __restrict__ csub, const uint_t* __restrict__ pkC,
                          uint_t* __restrict__ bcnt, uint_t* __restrict__ kbuf) {
    __shared__ uint_t bmp[3125];
    __shared__ uint_t sh[256];
    int tid = threadIdx.x, bid = blockIdx.x;
    uint_t s = csub[bid], epos = csub[bid + 1];
    int n = (int)(epos - s);
    for (int i = tid; i < 3125; i += 256) bmp[i] = 0;
    __syncthreads();
    for (int i = tid; i < n; i += 256) {
        uint_t w = pkC[s + i];
        uint_t le = ((w >> 15) & 3u) * 25000u + (w & 32767u);
        atomicOr(&bmp[le >> 5], 1u << (le & 31u));
    }
    __syncthreads();
    int lo = tid * 13, hi = lo + 13;
    if (lo > 3125) lo = 3125;
    if (hi > 3125) hi = 3125;
    uint_t mine = 0;
    for (int i = lo; i < hi; ++i) mine += __popc(bmp[i]);
    sh[tid] = mine;
    __syncthreads();
    for (int off = 1; off < 256; off <<= 1) {
        uint_t v = (tid >= off) ? sh[tid - off] : 0u;
        __syncthreads();
        sh[tid] += v;
        __syncthreads();
    }
    uint_t r = sh[tid] - mine;
    uint_t kb = (uint_t)bid * KCAP;
    for (int i = lo; i < hi; ++i) {
        uint_t bits = bmp[i];
        while (bits) {
            int b = __builtin_ctz(bits);
            bits &= bits - 1u;
            if (r < KCAP) kbuf[kb + r] = (uint_t)i * 32u + (uint_t)b;
            r++;
        }
    }
    if (tid == 255) bcnt[bid] = min(sh[255], (uint_t)KCAP);
}

// K6t: zero only the unwritten tails of EI/ATTR (the full 32 MB memset was ~99.7%
// wasted — emit covers ranks [0,total)).
__global__ void tail_zero(const uint_t* __restrict__ ebase, float* __restrict__ out) {
    uint_t total = ebase[NSEG];
    uint_t idx = blockIdx.x * 256u + (uint_t)threadIdx.x;
    uint_t stride = gridDim.x * 256u;
    for (uint_t k = total + idx; k < EE; k += stride) {
        out[O_EI + k] = 0.f;
        out[O_EI + EE + k] = 0.f;
    }
    for (uint_t k = 3u * total + idx; k < 3u * EE; k += stride) {
        out[O_ATTR + k] = 0.f;
    }
}

// K6b: decode dense keys, write u/v COALESCED + attrs (np gathers are L2-resident).
// Global order: bid asc (= u-group asc), key asc within (= (u&3, v) asc) ->
// ascending enc, identical to jnp.unique output order.
__global__ void enc_emit(const uint_t* __restrict__ ebase, const uint_t* __restrict__ kbuf,
                         float* __restrict__ out) {
    int tid = threadIdx.x, bid = blockIdx.x;
    uint_t g0 = ebase[bid], g1 = ebase[bid + 1];
    int cnt = (int)(g1 - g0);
    const float* np = out + O_POS;
    uint_t ubase = ((uint_t)(bid >> 5)) * 128u + ((uint_t)(bid & 31)) * 4u;
    uint_t kb = (uint_t)bid * KCAP;
    for (int r = tid; r < cnt; r += 256) {
        uint_t le = kbuf[kb + r];
        uint_t uo = le / 25000u;
        uint_t v = le - uo * 25000u;
        uint_t u = ubase + uo;
        uint_t rank = g0 + (uint_t)r;
        out[O_EI + rank] = (float)u;
        out[O_EI + EE + rank] = (float)v;
        out[O_ATTR + (size_t)rank * 3 + 0] = np[v * 3 + 0] - np[u * 3 + 0];
        out[O_ATTR + (size_t)rank * 3 + 1] = np[v * 3 + 1] - np[u * 3 + 1];
        out[O_ATTR + (size_t)rank * 3 + 2] = np[v * 3 + 2] - np[u * 3 + 2];
    }
}

extern "C" void kernel_launch(void* const* d_in, const int* in_sizes, int n_in,
                              void* d_out, int out_size, void* d_ws, size_t ws_size,
                              hipStream_t stream) {
    const float* x     = (const float*)d_in[0];
    const float* pos   = (const float*)d_in[1];
    const int*   ei    = (const int*)d_in[2];
    const float* ea    = (const float*)d_in[3];
    const int*   batch = (const int*)d_in[4];
    const float* Wconv = (const float*)d_in[5];
    const float* Wedge = (const float*)d_in[6];
    // d_in[7] = D_bloom: dead (bloom_pos never reaches an output)
    const float* Wg    = (const float*)d_in[8];
    // d_in[9] = W_gattr: contribution cancels exactly within each cluster

    float*  out = (float*)d_out;
    uint_t* ws  = (uint_t*)d_ws;

    if (ws_size < (size_t)WS_WORDS * 4) return;

    ushort_t* m1b    = (ushort_t*)(ws + W_M1B);
    uint_t*   pkW    = ws + W_AGGB;             // sorted keys
    uint_t*   paggw  = ws + W_PAGG;
    uint4*    pk4    = (uint4*)(ws + W_PKA4);
    uint_t*   pkC    = ws + W_PKC;
    uint_t*   offs2  = ws + W_OFFS2;
    uint_t*   bhA2   = ws + W_BHA2;
    uint_t*   bhC    = ws + W_BHC;
    uint_t*   bbA2   = ws + W_BBA2;
    uint_t*   bcurA2 = ws + W_BCURA2;
    uint_t*   bbC    = ws + W_BBC;
    uint_t*   bcurC  = ws + W_BCURC;
    uint_t*   xb     = (uint_t*)(out + O_EI);   // 6.4M-word bf16-x staging in out region
    // dead-region reuse (valid after bucket_sort_A2 / gemm_tiled):
    uint_t*   csub   = ws + W_PKA4;             // u32 [NSEG+1]
    uint_t*   bcnt2  = ws + W_PKA4 + 8192u;     // u32 [NSEG]
    uint_t*   ebase2 = ws + W_PKA4 + 16384u;    // u32 [NSEG+1]
    uint_t*   kbuf   = ws + W_PAGG;             // u32 [NSEG*KCAP] = 6.42M <= 13.2M

    hipMemsetAsync(bhA2, 0, (size_t)(NBKT2 + NBKT) * 4, stream);   // bhA2 + bhC contiguous

    xpack<<<dim3(12500), dim3(256), 0, stream>>>((const float4*)x, (uint2*)xb);
    build_m1f<<<dim3(131), dim3(128), 0, stream>>>(Wconv, Wedge, Wg, m1b);
    edge_hist2<<<dim3(256), dim3(1024), 0, stream>>>(ei, bhA2, bhC);
    scan_small<<<dim3(1), dim3(256), 0, stream>>>(bhA2, bbA2, bcurA2, NBKT2);
    scan_small<<<dim3(1), dim3(256), 0, stream>>>(bhC, bbC, bcurC, NBKT);
    bucket_place_AC<<<dim3((EE + TPB - 1) / TPB), dim3(1024), 0, stream>>>(ei, ea, bcurA2, bcurC, pk4, pkC);
    bucket_sort_A2<<<dim3(NBKT2), dim3(256), 0, stream>>>(bbA2, pk4, pkW, paggw, offs2);
    cluster_pass<<<dim3(98), dim3(256), 0, stream>>>(pos, batch, out);
    cluster_reduce5<<<dim3(((CC + 4 * CPW - 1) / (4 * CPW)) * 8), dim3(256), 0, stream>>>(offs2, pkW, xb, paggw);
    gemm_tiled<<<dim3((CC + GEMM_CPB - 1) / GEMM_CPB), dim3(256), 0, stream>>>(paggw, m1b, out);
    bucket_sort_C<<<dim3(NBKT), dim3(256), 0, stream>>>(bbC, pkC, csub);
    enc_count<<<dim3(NSEG), dim3(256), 0, stream>>>(csub, pkC, bcnt2, kbuf);
    scan_small<<<dim3(1), dim3(256), 0, stream>>>(bcnt2, ebase2, (uint_t*)0, NSEG);
    tail_zero<<<dim3(512), dim3(256), 0, stream>>>(ebase2, out);
    enc_emit<<<dim3(NSEG), dim3(256), 0, stream>>>(ebase2, kbuf, out);
}